// Round 1
// baseline (198.347 us; speedup 1.0000x reference)
//
#include <hip/hip_runtime.h>
#include <hip/hip_bf16.h>
#include <math.h>

typedef __bf16 bf16x8 __attribute__((ext_vector_type(8)));
typedef __bf16 bf16x4 __attribute__((ext_vector_type(4)));
typedef float  f32x4  __attribute__((ext_vector_type(4)));

constexpr int Nn = 8192;   // B*S
constexpr int Dd = 256;    // feature dim
constexpr float LOG2E     = 1.4426950408889634f;
constexpr float SIM_SCALE = 20.0f * LOG2E;   // (1/tau)*log2(e), tau=0.05
constexpr float SIM_BIAS  = -20.0f * LOG2E;  // fixed max = 1/tau = 20 (|q.k|<=1)

// ---------------------------------------------------------------------------
// Kernel 1: L2-normalize rows of logits/labels, cast to bf16 into workspace.
// One wave per row (256 floats = 64 lanes x float4).
// ---------------------------------------------------------------------------
__global__ __launch_bounds__(256) void prep_kernel(const float* __restrict__ logits,
                                                   const float* __restrict__ labels,
                                                   __bf16* __restrict__ qb,
                                                   __bf16* __restrict__ kb) {
  const int gw   = (blockIdx.x * 256 + threadIdx.x) >> 6;  // global wave id
  const int lane = threadIdx.x & 63;
  const float* src;
  __bf16* dst;
  int row;
  if (gw < Nn) { src = logits; dst = qb; row = gw; }
  else         { src = labels; dst = kb; row = gw - Nn; }

  const float4 v = *reinterpret_cast<const float4*>(src + (size_t)row * Dd + lane * 4);
  float ss = v.x * v.x + v.y * v.y + v.z * v.z + v.w * v.w;
#pragma unroll
  for (int m = 32; m >= 1; m >>= 1) ss += __shfl_xor(ss, m);
  const float scale = 1.0f / fmaxf(sqrtf(ss), 1e-12f);

  bf16x4 o;
  o[0] = (__bf16)(v.x * scale);
  o[1] = (__bf16)(v.y * scale);
  o[2] = (__bf16)(v.z * scale);
  o[3] = (__bf16)(v.w * scale);
  *reinterpret_cast<bf16x4*>(dst + (size_t)row * Dd + lane * 4) = o;
}

// ---------------------------------------------------------------------------
// Kernel 2: per-column bias (-1e30 kills invalid columns inside exp2) and
// zero the per-row accumulators (ws is poisoned 0xAA before every call).
// ---------------------------------------------------------------------------
__global__ __launch_bounds__(256) void init_kernel(const int* __restrict__ pad,
                                                   float* __restrict__ cbias,
                                                   float* __restrict__ g_all,
                                                   float* __restrict__ g_pos) {
  const int j = blockIdx.x * 256 + threadIdx.x;
  cbias[j] = pad[j] ? 0.0f : -1e30f;
  g_all[j] = 0.0f;
  g_pos[j] = 0.0f;
}

// ---------------------------------------------------------------------------
// Kernel 3: fused sim = Q K^T / tau + masked exp-sum epilogue.
// Grid (64 row-tiles, 8 col-chunks). Block 256 = 4 waves; each block owns a
// 128-row stripe and 1024 columns (8 col-tiles of 128). Per col-tile:
// K-loop of 8 steps (BK=32) staging A/B chunks in padded LDS, 16 MFMAs
// (16x16x32 bf16) per wave per step; epilogue folds exp(sim-20) into
// per-row accumulators (all & positives) without materializing sim.
// ---------------------------------------------------------------------------
__global__ __launch_bounds__(256) void gemm_lse_kernel(const __bf16* __restrict__ qb,
                                                       const __bf16* __restrict__ kb,
                                                       const float* __restrict__ cbias,
                                                       const int* __restrict__ ad,
                                                       float* __restrict__ g_all,
                                                       float* __restrict__ g_pos) {
  constexpr int LDT = 40;  // LDS row stride (bf16): 32 + 8 pad -> 2-way conflicts only
  __shared__ __bf16 As[128 * LDT];
  __shared__ __bf16 Bs[128 * LDT];

  const int tid  = threadIdx.x;
  const int lane = tid & 63;
  const int w    = tid >> 6;           // wave 0..3
  const int wrow = (w >> 1) * 64;      // wave's row quadrant
  const int wcol = (w & 1) * 64;       // wave's col quadrant
  const int lq   = lane & 15;          // position within 16
  const int qd   = lane >> 4;          // quad 0..3
  const int rowBase  = blockIdx.x * 128;
  const int colChunk = blockIdx.y * 1024;

  // ad of the rows this lane owns in the C layout (row = wrow+mt*16+qd*4+r)
  int ad_i[4][4];
#pragma unroll
  for (int mt = 0; mt < 4; ++mt)
#pragma unroll
    for (int r = 0; r < 4; ++r)
      ad_i[mt][r] = ad[rowBase + wrow + mt * 16 + qd * 4 + r];

  float accA[4][4] = {};
  float accP[4][4] = {};

  // staging geometry: 512 segments of 16B per matrix chunk, 2 per thread
  const int s0row = tid >> 2;
  const int s1row = (tid + 256) >> 2;
  const int sq    = tid & 3;

  for (int ct = 0; ct < 8; ++ct) {
    const int colBase = colChunk + ct * 128;

    f32x4 c[4][4];
#pragma unroll
    for (int mt = 0; mt < 4; ++mt)
#pragma unroll
      for (int nt = 0; nt < 4; ++nt)
        c[mt][nt] = (f32x4){0.f, 0.f, 0.f, 0.f};

    for (int kk = 0; kk < 8; ++kk) {
      const int kOff = kk * 32;
      const float4 va0 = *reinterpret_cast<const float4*>(qb + (size_t)(rowBase + s0row) * Dd + kOff + sq * 8);
      const float4 vb0 = *reinterpret_cast<const float4*>(kb + (size_t)(colBase + s0row) * Dd + kOff + sq * 8);
      const float4 va1 = *reinterpret_cast<const float4*>(qb + (size_t)(rowBase + s1row) * Dd + kOff + sq * 8);
      const float4 vb1 = *reinterpret_cast<const float4*>(kb + (size_t)(colBase + s1row) * Dd + kOff + sq * 8);
      *reinterpret_cast<float4*>(&As[s0row * LDT + sq * 8]) = va0;
      *reinterpret_cast<float4*>(&Bs[s0row * LDT + sq * 8]) = vb0;
      *reinterpret_cast<float4*>(&As[s1row * LDT + sq * 8]) = va1;
      *reinterpret_cast<float4*>(&Bs[s1row * LDT + sq * 8]) = vb1;
      __syncthreads();

      bf16x8 af[4], bfr[4];
#pragma unroll
      for (int mt = 0; mt < 4; ++mt)
        af[mt] = *reinterpret_cast<const bf16x8*>(&As[(wrow + mt * 16 + lq) * LDT + qd * 8]);
#pragma unroll
      for (int nt = 0; nt < 4; ++nt)
        bfr[nt] = *reinterpret_cast<const bf16x8*>(&Bs[(wcol + nt * 16 + lq) * LDT + qd * 8]);

#pragma unroll
      for (int mt = 0; mt < 4; ++mt)
#pragma unroll
        for (int nt = 0; nt < 4; ++nt)
          c[mt][nt] = __builtin_amdgcn_mfma_f32_16x16x32_bf16(af[mt], bfr[nt], c[mt][nt], 0, 0, 0);
      __syncthreads();
    }

    // epilogue: e = exp(sim - 20) with invalid cols -> 0 via cbias = -1e30
#pragma unroll
    for (int nt = 0; nt < 4; ++nt) {
      const int col    = colBase + wcol + nt * 16 + lq;
      const float bias = SIM_BIAS + cbias[col];
      const int adj    = ad[col];
#pragma unroll
      for (int mt = 0; mt < 4; ++mt) {
#pragma unroll
        for (int r = 0; r < 4; ++r) {
          const float e = exp2f(fmaf(c[mt][nt][r], SIM_SCALE, bias));
          accA[mt][r] += e;
          accP[mt][r] += (adj == ad_i[mt][r]) ? e : 0.0f;
        }
      }
    }
  }

  // reduce the 16 column-lanes of each row, then one atomic per row per wave
#pragma unroll
  for (int mt = 0; mt < 4; ++mt) {
#pragma unroll
    for (int r = 0; r < 4; ++r) {
      float a = accA[mt][r];
      float p = accP[mt][r];
#pragma unroll
      for (int m = 1; m < 16; m <<= 1) {
        a += __shfl_xor(a, m);
        p += __shfl_xor(p, m);
      }
      if (lq == 0) {
        const int row = rowBase + wrow + mt * 16 + qd * 4 + r;
        atomicAdd(&g_all[row], a);
        atomicAdd(&g_pos[row], p);
      }
    }
  }
}

// ---------------------------------------------------------------------------
// Kernel 4: loss = mean over valid rows of log(g_all) - log(g_pos).
// (has_pos == valid: a valid row always has its own diagonal as positive.)
// ---------------------------------------------------------------------------
__global__ __launch_bounds__(256) void reduce_kernel(const float* __restrict__ g_all,
                                                     const float* __restrict__ g_pos,
                                                     const int* __restrict__ pad,
                                                     float* __restrict__ out) {
  __shared__ float sS[4], sC[4];
  const int t = threadIdx.x;
  float s = 0.f, c = 0.f;
  for (int i = t; i < Nn; i += 256) {
    if (pad[i]) {
      s += logf(g_all[i]) - logf(g_pos[i]);
      c += 1.0f;
    }
  }
#pragma unroll
  for (int m = 32; m >= 1; m >>= 1) {
    s += __shfl_xor(s, m);
    c += __shfl_xor(c, m);
  }
  if ((t & 63) == 0) { sS[t >> 6] = s; sC[t >> 6] = c; }
  __syncthreads();
  if (t == 0) {
    const float S = sS[0] + sS[1] + sS[2] + sS[3];
    const float C = sC[0] + sC[1] + sC[2] + sC[3];
    out[0] = S / fmaxf(C, 1.0f);
  }
}

extern "C" void kernel_launch(void* const* d_in, const int* in_sizes, int n_in,
                              void* d_out, int out_size, void* d_ws, size_t ws_size,
                              hipStream_t stream) {
  const float* logits = (const float*)d_in[0];
  const float* labels = (const float*)d_in[1];
  const int*   pad    = (const int*)d_in[2];
  const int*   ad     = (const int*)d_in[3];

  char* ws = (char*)d_ws;
  __bf16* qb   = (__bf16*)(ws);                 // 8192*256*2 = 4 MiB
  __bf16* kb   = (__bf16*)(ws + 4194304);       // 4 MiB
  float*  cb   = (float*)(ws + 8388608);        // 32 KiB
  float*  gAll = (float*)(ws + 8421376);        // 32 KiB
  float*  gPos = (float*)(ws + 8454144);        // 32 KiB
  float*  out  = (float*)d_out;

  prep_kernel<<<4096, 256, 0, stream>>>(logits, labels, qb, kb);
  init_kernel<<<32, 256, 0, stream>>>(pad, cb, gAll, gPos);
  gemm_lse_kernel<<<dim3(64, 8), 256, 0, stream>>>(qb, kb, cb, ad, gAll, gPos);
  reduce_kernel<<<1, 256, 0, stream>>>(gAll, gPos, pad, out);
}